// Round 6
// baseline (82.318 us; speedup 1.0000x reference)
//
#include <hip/hip_runtime.h>
#include <hip/hip_bf16.h>

// out[t][c] = x[t][768+c] + sum_d x[t][(c>>6)*256+d] * Wv[c&63][d]
// t in [0,65536), c in [0,256). Everything else in the reference is dead code.
//
// v6: contiguous-read restructure. Each global load instr = dense 1 KB burst
// from ONE token row (v4 gathered 16 x 128 B at 4 KB stride -> HBM channel
// imbalance, stuck at 4.4 TB/s). Chunk of 16 tokens staged to LDS as bf16
// (XOR-swizzled), double-buffered; waves split output by head; W_v fragments
// live in registers for the whole block.

#define TOKENS_PER_BLOCK 128
#define NCHUNK 8                                  // 16 tokens per chunk
#define NBLOCKS (16 * 4096 / TOKENS_PER_BLOCK)    // 512

typedef short bf16x4 __attribute__((ext_vector_type(4)));
typedef short bf16x8 __attribute__((ext_vector_type(8)));
typedef float f32x4  __attribute__((ext_vector_type(4)));

__device__ __forceinline__ short f2bf(float f) {
    __hip_bfloat16 h = __float2bfloat16(f);
    return __builtin_bit_cast(short, h);
}
__device__ __forceinline__ bf16x4 cvt4(f32x4 a) {
    bf16x4 r;
    r[0] = f2bf(a[0]); r[1] = f2bf(a[1]); r[2] = f2bf(a[2]); r[3] = f2bf(a[3]);
    return r;
}
__device__ __forceinline__ bf16x8 cvt8(f32x4 a, f32x4 b) {
    bf16x8 r;
    r[0] = f2bf(a[0]); r[1] = f2bf(a[1]); r[2] = f2bf(a[2]); r[3] = f2bf(a[3]);
    r[4] = f2bf(b[0]); r[5] = f2bf(b[1]); r[6] = f2bf(b[2]); r[7] = f2bf(b[3]);
    return r;
}

// X chunk in LDS: [16 tok][1024 col] bf16, row stride 2048 B.
// XOR swizzle spreads the stride-2048 fragment reads across banks
// (2-way residual aliasing = free per m136).
__device__ __forceinline__ int xofs(int tok, int colbyte) {
    return tok * 2048 + (colbyte ^ ((tok & 7) << 4));
}

__global__ __launch_bounds__(256, 1) void mha_vcat_kernel(
    const float* __restrict__ x, const float* __restrict__ Wv,
    float* __restrict__ out)
{
    __shared__ char X[2][16 * 2048];  // 2 x 32 KiB

    const int tid  = threadIdx.x;
    const int wid  = tid >> 6;        // wave = output head
    const int lane = tid & 63;
    const int cl   = lane & 15;       // MFMA col lane: token within chunk
    const int g    = lane >> 4;       // lane group: k-slice / D row group

    const long blockTok = (long)blockIdx.x * TOKENS_PER_BLOCK;

    // Staging role: per p-step, 256 threads cover 2 full rows densely.
    const int srow  = tid >> 7;       // which row of the pair
    const int scolA = (tid & 127) * 4;  // float col of part A; part B at +512

    // ---- Issue chunk-0 stage loads first (dense 1 KB per wave-instr).
    f32x4 sA[8], sB[8];
    #pragma unroll
    for (int p = 0; p < 8; ++p) {
        const float* q = x + (blockTok + p * 2 + srow) * 1024;
        sA[p] = *(const f32x4*)(q + scolA);
        sB[p] = *(const f32x4*)(q + 512 + scolA);
    }

    // ---- W_v fragments, direct from global (64 KB, L2/L3-resident),
    // held in registers for the whole block. wfr[kk][n].
    bf16x8 wfr[8][4];
    #pragma unroll
    for (int kk = 0; kk < 8; ++kk)
        #pragma unroll
        for (int n = 0; n < 4; ++n) {
            const float* q = Wv + (n * 16 + cl) * 256 + kk * 32 + g * 8;
            wfr[kk][n] = cvt8(*(const f32x4*)q, *(const f32x4*)(q + 4));
        }

    // Identity A-fragments for the residual (I * X3slice^T).
    bf16x8 diag0, diag1;
    #pragma unroll
    for (int j = 0; j < 8; ++j) {
        diag0[j] = (g * 8 + j == cl)      ? f2bf(1.0f) : (short)0;
        diag1[j] = (g * 8 + j == cl + 16) ? f2bf(1.0f) : (short)0;
    }

    // ---- Write chunk 0 to LDS.
    #pragma unroll
    for (int p = 0; p < 8; ++p) {
        const int lt = p * 2 + srow;
        *(bf16x4*)(&X[0][xofs(lt, scolA * 2)])        = cvt4(sA[p]);
        *(bf16x4*)(&X[0][xofs(lt, 1024 + scolA * 2)]) = cvt4(sB[p]);
    }
    __syncthreads();

    #pragma unroll
    for (int c = 0; c < NCHUNK; ++c) {
        // Issue next chunk's loads; they fly during compute.
        if (c < NCHUNK - 1) {
            #pragma unroll
            for (int p = 0; p < 8; ++p) {
                const float* q = x + (blockTok + (c + 1) * 16 + p * 2 + srow) * 1024;
                sA[p] = *(const f32x4*)(q + scolA);
                sB[p] = *(const f32x4*)(q + 512 + scolA);
            }
        }

        // ---- Compute chunk c: wave wid does channels [wid*64, wid*64+64).
        const char* Xb = X[c & 1];
        f32x4 acc[4];
        #pragma unroll
        for (int n = 0; n < 4; ++n) acc[n] = (f32x4){0.f, 0.f, 0.f, 0.f};

        #pragma unroll
        for (int kk = 0; kk < 8; ++kk) {
            const bf16x8 xf = *(const bf16x8*)(
                Xb + xofs(cl, wid * 512 + kk * 64 + g * 16));
            #pragma unroll
            for (int n = 0; n < 4; ++n)
                acc[n] = __builtin_amdgcn_mfma_f32_16x16x32_bf16(
                    wfr[kk][n], xf, acc[n], 0, 0, 0);
        }
        // Residual: channels wid*64 + [0,64) += x[:, 768 + wid*64 + [0,64)).
        #pragma unroll
        for (int s = 0; s < 2; ++s) {
            const bf16x8 x3 = *(const bf16x8*)(
                Xb + xofs(cl, 1536 + wid * 128 + s * 64 + g * 16));
            acc[2 * s]     = __builtin_amdgcn_mfma_f32_16x16x32_bf16(
                diag0, x3, acc[2 * s], 0, 0, 0);
            acc[2 * s + 1] = __builtin_amdgcn_mfma_f32_16x16x32_bf16(
                diag1, x3, acc[2 * s + 1], 0, 0, 0);
        }

        // D: col(=token)=lane&15, row(=channel)=g*4+j -> dwordx4 stores.
        float* trow = out + (blockTok + c * 16 + cl) * 256 + wid * 64;
        #pragma unroll
        for (int n = 0; n < 4; ++n)
            *(f32x4*)(trow + n * 16 + g * 4) = acc[n];

        // ---- Publish next chunk.
        if (c < NCHUNK - 1) {
            __syncthreads();
            char* Xn = X[(c + 1) & 1];
            #pragma unroll
            for (int p = 0; p < 8; ++p) {
                const int lt = p * 2 + srow;
                *(bf16x4*)(&Xn[xofs(lt, scolA * 2)])        = cvt4(sA[p]);
                *(bf16x4*)(&Xn[xofs(lt, 1024 + scolA * 2)]) = cvt4(sB[p]);
            }
            __syncthreads();
        }
    }
}

extern "C" void kernel_launch(void* const* d_in, const int* in_sizes, int n_in,
                              void* d_out, int out_size, void* d_ws, size_t ws_size,
                              hipStream_t stream) {
    const float* x  = (const float*)d_in[0];
    const float* Wv = (const float*)d_in[3];  // x, W_q, W_k, W_v
    float* out = (float*)d_out;
    mha_vcat_kernel<<<dim3(NBLOCKS), dim3(256), 0, stream>>>(x, Wv, out);
}

// Round 7
// 78.397 us; speedup vs baseline: 1.0500x; 1.0500x over previous
//
#include <hip/hip_runtime.h>
#include <hip/hip_bf16.h>

// out[t][c] = x[t][768+c] + sum_d x[t][(c>>6)*256+d] * Wv[c&63][d]
// t in [0,65536), c in [0,256). Everything else in the reference is dead code.
//
// v7: global_load_lds staging (zero-VGPR in-flight depth), single 64 KB f32
// chunk buffer (16 tok x 4 KB), 2 blocks/CU covering each other's bubbles.
// Source-side XOR swizzle (m173) -> conflict-free ds_read_b128 fragments.

#define NTOK (16 * 4096)
#define TPB  64                 // tokens per block
#define NCH  4                  // chunks of 16 tokens
#define NBLK (NTOK / TPB)       // 1024

typedef short bf16x8 __attribute__((ext_vector_type(8)));
typedef float f32x4  __attribute__((ext_vector_type(4)));

__device__ __forceinline__ short f2bf(float f) {
    __hip_bfloat16 h = __float2bfloat16(f);
    return __builtin_bit_cast(short, h);
}
__device__ __forceinline__ bf16x8 cvt8(f32x4 a, f32x4 b) {
    bf16x8 r;
    r[0] = f2bf(a[0]); r[1] = f2bf(a[1]); r[2] = f2bf(a[2]); r[3] = f2bf(a[3]);
    r[4] = f2bf(b[0]); r[5] = f2bf(b[1]); r[6] = f2bf(b[2]); r[7] = f2bf(b[3]);
    return r;
}

__global__ __launch_bounds__(256, 2) void mha_vcat_kernel(
    const float* __restrict__ x, const float* __restrict__ Wv,
    float* __restrict__ out)
{
    __shared__ float Xf[16 * 1024];   // 64 KiB: 16 tokens x 4 KB (f32)

    const int tid  = threadIdx.x;
    const int w    = tid >> 6;        // wave id = output head
    const int lane = tid & 63;
    const int cl   = lane & 15;       // MFMA col lane = local token
    const int g    = lane >> 4;

    const long blockTok = (long)blockIdx.x * TPB;

    // ---- stage(c): 64 x global_load_lds_dwordx4, zero VGPR in flight.
    // LDS dest is wave-uniform base + lane*16 (linear, as HW requires).
    // Global source lane offset is XOR-swizzled per token (same dense 1 KB
    // span -> coalescing preserved; read back with the same XOR).
    auto stage = [&](int c) {
        #pragma unroll
        for (int i = 0; i < 16; ++i) {
            const int tok = w * 4 + (i >> 2);   // local token [0,16)
            const int q   = i & 3;              // 1 KB quarter of the row
            const char* gp = (const char*)x
                + (blockTok + c * 16 + tok) * 4096 + q * 1024
                + ((lane * 16) ^ ((tok & 7) << 4));
            float* lp = &Xf[tok * 1024 + q * 256];   // wave-uniform
            __builtin_amdgcn_global_load_lds(
                (const __attribute__((address_space(1))) void*)gp,
                (__attribute__((address_space(3))) void*)lp, 16, 0, 0);
        }
    };

    stage(0);

    // ---- W_v fragments in registers (64 KB, L2/L3-resident); overlap with
    // chunk-0 flight. wfr[kk][n]: B-rows n*16+cl, k-slice kk*32+g*8.
    bf16x8 wfr[8][4];
    #pragma unroll
    for (int kk = 0; kk < 8; ++kk)
        #pragma unroll
        for (int n = 0; n < 4; ++n) {
            const float* q = Wv + (n * 16 + cl) * 256 + kk * 32 + g * 8;
            wfr[kk][n] = cvt8(*(const f32x4*)q, *(const f32x4*)(q + 4));
        }

    const int swz = (cl & 7) << 4;
    const char* myrow = (const char*)Xf + cl * 4096;

    for (int c = 0; c < NCH; ++c) {
        __syncthreads();   // drains vmcnt(0): chunk c (+Wv on c=0) landed

        // ---- compute chunk c: wave w does channels [w*64, w*64+64).
        f32x4 acc[4];
        #pragma unroll
        for (int n = 0; n < 4; ++n) acc[n] = (f32x4){0.f, 0.f, 0.f, 0.f};

        #pragma unroll
        for (int kk = 0; kk < 8; ++kk) {
            const int b = w * 1024 + kk * 128 + g * 32;   // logical byte
            const f32x4 lo = *(const f32x4*)(myrow + ((b)      ^ swz));
            const f32x4 hi = *(const f32x4*)(myrow + ((b + 16) ^ swz));
            const bf16x8 xf = cvt8(lo, hi);
            #pragma unroll
            for (int n = 0; n < 4; ++n)
                acc[n] = __builtin_amdgcn_mfma_f32_16x16x32_bf16(
                    wfr[kk][n], xf, acc[n], 0, 0, 0);
        }

        // Residual (exact f32) + store. acc[n][j] = channel w*64+n*16+g*4+j
        // of token cl -> residual floats at 768 + same channel.
        float* trow = out + (blockTok + c * 16 + cl) * 256 + w * 64;
        #pragma unroll
        for (int n = 0; n < 4; ++n) {
            const int rb = 3072 + w * 256 + n * 64 + g * 16;  // byte of x3 slice
            const f32x4 r = *(const f32x4*)(myrow + (rb ^ swz));
            acc[n] += r;
            *(f32x4*)(trow + n * 16 + g * 4) = acc[n];
        }

        __syncthreads();   // all waves done reading Xf before restage
        if (c + 1 < NCH) stage(c + 1);
    }
}

extern "C" void kernel_launch(void* const* d_in, const int* in_sizes, int n_in,
                              void* d_out, int out_size, void* d_ws, size_t ws_size,
                              hipStream_t stream) {
    const float* x  = (const float*)d_in[0];
    const float* Wv = (const float*)d_in[3];  // x, W_q, W_k, W_v
    float* out = (float*)d_out;
    mha_vcat_kernel<<<dim3(NBLK), dim3(256), 0, stream>>>(x, Wv, out);
}